// Round 1
// baseline (140.583 us; speedup 1.0000x reference)
//
#include <hip/hip_runtime.h>

// VectorQuantizer: B=16, D=64, H=64, W=64, K=1024
#define DD 64
#define KK 1024
#define NPTS 65536
#define TOTAL 4194304

// Output layout (flat f32): quantized[4194304], L1, L2, idx[65536]
#define OFF_L1 4194304
#define OFF_L2 4194305
#define OFF_IDX 4194306

// ws layout (bytes): [0] f32 sum, [8] u32 ticket, enh @ float 64 (byte 256),
// ehT @ byte 65536 (128KB), elT @ byte 196608 (128KB). (<=328KB used)
#define WS_ENH_F 64
#define WS_EHT_BYTE 65536
#define WS_ELT_BYTE (65536 + 131072)

// score = dot(x,e) + 512 - ||e||^2/2  (argmax == argmin distance; +512 keeps
// all scores positive so float bits are monotone -> packed uint compare).
// Rescue margin: 32-ulp granule (<=2e-3) + bf16x3 err (~6e-4) + slack.
#define MARGIN_S 0.006f

typedef __attribute__((ext_vector_type(8))) short short8;
typedef __attribute__((ext_vector_type(4))) float f32x4;

__device__ __forceinline__ unsigned short bf16_rne(float f) {
    unsigned b = __float_as_uint(f);
    return (unsigned short)((b + 0x7FFFu + ((b >> 16) & 1u)) >> 16);
}
__device__ __forceinline__ float bf16_to_f(unsigned short h) {
    return __uint_as_float(((unsigned)h) << 16);
}
__device__ __forceinline__ unsigned umax(unsigned a, unsigned b) { return a > b ? a : b; }
__device__ __forceinline__ unsigned umin(unsigned a, unsigned b) { return a < b ? a : b; }
// async global->LDS DMA, 16B per lane; LDS dest = wave-uniform base + lane*16
__device__ __forceinline__ void gld_lds16(const void* g, void* l) {
    __builtin_amdgcn_global_load_lds(
        (const __attribute__((address_space(1))) void*)g,
        (__attribute__((address_space(3))) void*)l, 16, 0, 0);
}
// swizzled position of element d within a 64-elem row r (16B-granule XOR key)
__device__ __forceinline__ int swz(int r, int d) {
    return ((d & ~7) ^ ((r & 7) << 3)) | (d & 7);
}

// ---------- kernel 1: enh + swizzled bf16 hi/lo codebook [k][64] ----------
__global__ __launch_bounds__(256) void prep_kernel(const float* __restrict__ e,
                                                   float* __restrict__ enh,
                                                   unsigned short* __restrict__ ehT,
                                                   unsigned short* __restrict__ elT,
                                                   float* __restrict__ sum,
                                                   unsigned* __restrict__ tick) {
    const int tid = threadIdx.x;
    if (blockIdx.x == 0 && tid == 0) { *sum = 0.f; *tick = 0u; }
    const int wave = tid >> 6, lane = tid & 63;
    const int k = blockIdx.x * 4 + wave;      // this wave's code
    const float v = e[lane * KK + k];         // lane = d
    const unsigned short h = bf16_rne(v);
    const unsigned short l = bf16_rne(v - bf16_to_f(h));
    const int pos = k * 64 + swz(k, lane);
    ehT[pos] = h;
    elT[pos] = l;
    float s2 = v * v;
#pragma unroll
    for (int m = 32; m > 0; m >>= 1) s2 += __shfl_down(s2, m, 64);
    if (lane == 0) enh[k] = 512.0f - 0.5f * s2;
}

// ---------- kernel 2: MFMA bf16x3 + packed-key argmax + in-block exact rescue
//            + quantize (bf16 hi+lo reconstruct) + loss via score identity ----------
// 256 thr = 4 waves; block = 64 pts x 1024 codes (16 tiles of 64 codes).
// LDS = exactly 32KB (ebuf double buffer); x-prep and merge scratch alias into
// ebuf -> 5 blocks/CU capacity, whole 1024-block grid co-resident (4/CU).
__global__ __launch_bounds__(256, 5) void vq_gemm(const float* __restrict__ x,
                                                  const float* __restrict__ e,
                                                  const float* __restrict__ enh,
                                                  const unsigned short* __restrict__ ehT,
                                                  const unsigned short* __restrict__ elT,
                                                  float* __restrict__ out,
                                                  float* __restrict__ sum,
                                                  unsigned* __restrict__ tick) {
    __shared__ __align__(16) char ebuf[2 * 16384];   // the ONLY LDS (32KB)

    // post-loop aliases into ebuf[0] (holds tile 14; dead once every wave has
    // passed kt=15's top barrier -- kt=15 reads only ebuf[1])
    float* mv1 = (float*)ebuf;          // [128]
    float* mv2 = mv1 + 128;             // [128]
    int*   mi1 = (int*)(mv2 + 128);     // [128]
    int*   ks  = mi1 + 128;             // [64]
    float* xnp = (float*)(ks + 64);     // [64]  ||x_p||^2
    float* lv  = xnp + 64;              // [64]  per-point loss term
    float* xp  = lv + 64;               // [64]  rescue point
    int*   rl  = (int*)(xp + 64);       // [64]  ambiguous-point list
    int*   rn  = rl + 64;               // [1]
    float* rv  = (float*)(rn + 1);      // [4]
    int*   ri  = (int*)(rv + 4);        // [4]

    const int tid = threadIdx.x;
    const int wave = tid >> 6, lane = tid & 63;
    const int n0 = blockIdx.x * 64;
    const int b = n0 >> 12;
    const int hw0 = n0 & 4095;

    const char* ehTb = (const char*)ehT;
    const char* elTb = (const char*)elT;
    const int lofs = wave * 1024 + lane * 16;   // per-lane byte offset in a pass

    // issue tile-0 DMA immediately (lands during x-prep)
    {
        char* db = ebuf;
        gld_lds16(ehTb + lofs,        db + wave * 1024);
        gld_lds16(ehTb + 4096 + lofs, db + 4096 + wave * 1024);
        gld_lds16(elTb + lofs,        db + 8192 + wave * 1024);
        gld_lds16(elTb + 4096 + lofs, db + 12288 + wave * 1024);
    }

    // ---- x prep, entirely inside ebuf[1]: fp32 stage -> regs -> bf16 hi/lo ----
    float* xsc = (float*)(ebuf + 16384);        // 16KB fp32 scratch (= buf1)
    {
        const int d = tid >> 2, ph = tid & 3;
        const float* src = x + ((b * DD + d) << 12) + hw0 + ph * 16;
        float* dst = xsc + d * 64 + ph * 16;
#pragma unroll
        for (int j = 0; j < 4; ++j)
            *(float4*)(dst + j * 4) = *(const float4*)(src + j * 4);
    }
    __syncthreads();
    const int p = tid >> 2, dq = tid & 3;
    float xv[16];
    float xn = 0.f;
#pragma unroll
    for (int s = 0; s < 16; ++s) {
        xv[s] = xsc[(dq * 16 + s) * 64 + p];
        xn = fmaf(xv[s], xv[s], xn);
    }
    xn += __shfl_down(xn, 1, 64);
    xn += __shfl_down(xn, 2, 64);   // dq==0 lane now holds ||x_p||^2
    __syncthreads();                // all xsc reads done; safe to overwrite
    unsigned short* xbh = (unsigned short*)(ebuf + 16384);
    unsigned short* xbl = (unsigned short*)(ebuf + 16384 + 8192);
    {
#pragma unroll
        for (int g = 0; g < 2; ++g) {
            short8 hh, ll;
#pragma unroll
            for (int j = 0; j < 8; ++j) {
                const float f = xv[g * 8 + j];
                const unsigned short h = bf16_rne(f);
                hh[j] = (short)h;
                ll[j] = (short)bf16_rne(f - bf16_to_f(h));
            }
            const int pos = p * 64 + ((dq * 16 + g * 8) ^ ((p & 7) << 3));
            *(short8*)(xbh + pos) = hh;
            *(short8*)(xbl + pos) = ll;
        }
    }
    __syncthreads();

    const int ln15 = lane & 15, q8 = (lane >> 4) * 8;
    const int wp = (wave >> 1) * 32;   // point base of this wave
    const int wc = (wave & 1) * 32;    // code base within tile

    short8 ah[2][2], al[2][2];         // persistent A frags [rf][kc]
#pragma unroll
    for (int rf = 0; rf < 2; ++rf)
#pragma unroll
        for (int kc = 0; kc < 2; ++kc) {
            const int pp = wp + rf * 16 + ln15;
            const int pos = pp * 64 + ((kc * 32 + q8) ^ ((pp & 7) << 3));
            ah[rf][kc] = *(const short8*)(xbh + pos);
            al[rf][kc] = *(const short8*)(xbl + pos);
        }

    unsigned v1u[8], v2u[8];
#pragma unroll
    for (int r = 0; r < 8; ++r) { v1u[r] = 0u; v2u[r] = 0u; }

    for (int kt = 0; kt < 16; ++kt) {
        __syncthreads();   // drains tile-kt DMA + all waves done with kt-1
        if (kt < 15) {     // stream tile kt+1 into the other buffer
            const int nkt = kt + 1;
            char* db = ebuf + (nkt & 1) * 16384;
            const char* sH = ehTb + nkt * 8192 + lofs;
            const char* sL = elTb + nkt * 8192 + lofs;
            gld_lds16(sH,        db + wave * 1024);
            gld_lds16(sH + 4096, db + 4096 + wave * 1024);
            gld_lds16(sL,        db + 8192 + wave * 1024);
            gld_lds16(sL + 4096, db + 12288 + wave * 1024);
        }
        const unsigned short* ebH = (const unsigned short*)(ebuf + (kt & 1) * 16384);
        const unsigned short* ebL = ebH + 4096;

        // acc init = 512 - ||e||^2/2 (biased argmax score)
        f32x4 acc[2][2];
#pragma unroll
        for (int cf = 0; cf < 2; ++cf) {
            const float ec = enh[kt * 64 + wc + cf * 16 + ln15];
#pragma unroll
            for (int rf = 0; rf < 2; ++rf)
                acc[rf][cf] = (f32x4){ec, ec, ec, ec};
        }

#pragma unroll
        for (int kc = 0; kc < 2; ++kc) {
            short8 bh[2], bl[2];
#pragma unroll
            for (int cf = 0; cf < 2; ++cf) {
                const int c = wc + cf * 16 + ln15;
                const int pos = c * 64 + ((kc * 32 + q8) ^ ((c & 7) << 3));
                bh[cf] = *(const short8*)(ebH + pos);
                bl[cf] = *(const short8*)(ebL + pos);
            }
#pragma unroll
            for (int rf = 0; rf < 2; ++rf)
#pragma unroll
                for (int cf = 0; cf < 2; ++cf) {
                    acc[rf][cf] = __builtin_amdgcn_mfma_f32_16x16x32_bf16(al[rf][kc], bh[cf], acc[rf][cf], 0, 0, 0);
                    acc[rf][cf] = __builtin_amdgcn_mfma_f32_16x16x32_bf16(ah[rf][kc], bl[cf], acc[rf][cf], 0, 0, 0);
                    acc[rf][cf] = __builtin_amdgcn_mfma_f32_16x16x32_bf16(ah[rf][kc], bh[cf], acc[rf][cf], 0, 0, 0);
                }
        }

        // packed-key top-2 per (rf,reg) row: key = (bits|31) ^ col5
        // (low5 = 31^col5 -> umax tie-breaks toward SMALLER col5 = smaller k)
#pragma unroll
        for (int rf = 0; rf < 2; ++rf)
#pragma unroll
            for (int reg = 0; reg < 4; ++reg) {
                const int r = rf * 4 + reg;
                const unsigned k0 = (__float_as_uint(acc[rf][0][reg]) | 31u) ^ (unsigned)(kt * 2 + 0);
                const unsigned k1 = (__float_as_uint(acc[rf][1][reg]) | 31u) ^ (unsigned)(kt * 2 + 1);
                const unsigned a = umax(k0, k1), bb = umin(k0, k1);
                v2u[r] = umax(umax(v2u[r], umin(v1u[r], a)), bb);
                v1u[r] = umax(v1u[r], a);
            }
    }

    // ebuf[0] is now dead (kt=15 read ebuf[1]); publish prologue-held state
    if ((tid & 3) == 0) xnp[p] = xn;
    if (tid == 0) *rn = 0;

    // decode + cross-lane merge within the 16 lanes sharing each row-set
#pragma unroll
    for (int r = 0; r < 8; ++r) {
        const unsigned c5 = 31u - (v1u[r] & 31u);
        int col = (int)(c5 >> 1) * 64 + wc + (int)(c5 & 1) * 16 + ln15;
        float val = __uint_as_float(v1u[r] & ~31u);
        float sec = __uint_as_float(v2u[r] & ~31u);
#pragma unroll
        for (int msk = 1; msk < 16; msk <<= 1) {
            const float ov = __shfl_xor(val, msk);
            const int oc = __shfl_xor(col, msk);
            const float os = __shfl_xor(sec, msk);
            sec = fmaxf(fmaxf(sec, os), fminf(val, ov));
            const bool t = (ov > val) || (ov == val && oc < col);
            val = t ? ov : val;
            col = t ? oc : col;
        }
        if (ln15 == 0) {
            const int q = lane >> 4;
            const int h = wave & 1;
            const int pt = wp + (r >> 2) * 16 + q * 4 + (r & 3);
            mv1[pt * 2 + h] = val;
            mi1[pt * 2 + h] = col;
            mv2[pt * 2 + h] = sec;
        }
    }
    __syncthreads();
    if (tid < 64) {   // merge the two code-half waves (argmax, tie -> smaller idx)
        const float va = mv1[tid * 2], vb = mv1[tid * 2 + 1];
        const int ia = mi1[tid * 2], ib = mi1[tid * 2 + 1];
        const bool t = (vb > va) || (vb == va && ib < ia);
        const float bv = t ? vb : va;
        const int bi = t ? ib : ia;
        const float sec = fmaxf(fmaxf(mv2[tid * 2], mv2[tid * 2 + 1]), fminf(va, vb));
        ks[tid] = bi;
        // loss via identity: ||x-e||^2 = ||x||^2 + 1024 - 2*score
        lv[tid] = xnp[tid] + 1024.0f - 2.0f * bv;
        if (bv - sec < MARGIN_S) {    // ambiguous under granule+bf16x3 bound
            const int w = atomicAdd(rn, 1);
            rl[w] = tid;              // <=64 entries possible
        }
    }
    __syncthreads();

    // ---- in-block exact fp32 rescue (expected ~0.16 items/block) ----
    const int lcnt = *rn;
    for (int it = 0; it < lcnt; ++it) {
        const int pr = rl[it];
        if (tid < 64) xp[tid] = x[((b * DD + tid) << 12) + hw0 + pr];
        __syncthreads();
        float d0 = 0.f, d1 = 0.f, d2 = 0.f, d3 = 0.f;
#pragma unroll 8
        for (int dd = 0; dd < DD; ++dd) {
            const float xd = xp[dd];
            const float4 ev = *(const float4*)(e + dd * KK + tid * 4);
            d0 = fmaf(xd, ev.x, d0);
            d1 = fmaf(xd, ev.y, d1);
            d2 = fmaf(xd, ev.z, d2);
            d3 = fmaf(xd, ev.w, d3);
        }
        const float4 ea = *(const float4*)(enh + tid * 4);
        float bs = d0 + ea.x;
        int bi2 = tid * 4;
        if (d1 + ea.y > bs) { bs = d1 + ea.y; bi2 = tid * 4 + 1; }
        if (d2 + ea.z > bs) { bs = d2 + ea.z; bi2 = tid * 4 + 2; }
        if (d3 + ea.w > bs) { bs = d3 + ea.w; bi2 = tid * 4 + 3; }
#pragma unroll
        for (int m = 1; m < 64; m <<= 1) {
            const float ov = __shfl_xor(bs, m, 64);
            const int oi = __shfl_xor(bi2, m, 64);
            if (ov > bs || (ov == bs && oi < bi2)) { bs = ov; bi2 = oi; }
        }
        if (lane == 0) { rv[wave] = bs; ri[wave] = bi2; }
        __syncthreads();
        if (tid == 0) {
            float gs = rv[0];
            int gi = ri[0];
#pragma unroll
            for (int t2 = 1; t2 < 4; ++t2)
                if (rv[t2] > gs || (rv[t2] == gs && ri[t2] < gi)) { gs = rv[t2]; gi = ri[t2]; }
            ks[pr] = gi;
            lv[pr] = xnp[pr] + 1024.0f - 2.0f * gs;   // exact score
        }
        __syncthreads();
    }

    // ---- idx out + block loss add + ticketed grid finalize ----
    if (tid < 64) {
        out[OFF_IDX + n0 + tid] = (float)ks[tid];
        float lc = lv[tid];
#pragma unroll
        for (int off = 32; off > 0; off >>= 1) lc += __shfl_down(lc, off, 64);
        if (tid == 0) {
            atomicAdd(sum, lc);
            __threadfence();
            const unsigned old = atomicAdd(tick, 1u);
            if (old == (unsigned)(gridDim.x - 1)) {
                const float s = atomicAdd(sum, 0.0f);
                const float m = s * (1.0f / (float)TOTAL);
                out[OFF_L1] = m;   // dictionary_loss
                out[OFF_L2] = m;   // commitment_loss (numerically identical)
            }
        }
    }

    // ---- quantize epilogue: reconstruct e from bf16 hi+lo (err <= ~3e-5) ----
    {
        const int pe = tid & 63, dqr = tid >> 6;
        const int kp = ks[pe];
        const int kx = (kp & 7) << 3;
        float qa[16];
#pragma unroll
        for (int g = 0; g < 2; ++g) {
            const int pos = kp * 64 + ((dqr * 16 + g * 8) ^ kx);
            const short8 h8 = *(const short8*)(ehT + pos);
            const short8 l8 = *(const short8*)(elT + pos);
#pragma unroll
            for (int j = 0; j < 8; ++j)
                qa[g * 8 + j] = bf16_to_f((unsigned short)h8[j]) + bf16_to_f((unsigned short)l8[j]);
        }
        float* ob = out + ((b * DD + dqr * 16) << 12) + hw0 + pe;
#pragma unroll
        for (int s = 0; s < 16; ++s) ob[s << 12] = qa[s];
    }
}

extern "C" void kernel_launch(void* const* d_in, const int* in_sizes, int n_in,
                              void* d_out, int out_size, void* d_ws, size_t ws_size,
                              hipStream_t stream) {
    const float* x = (const float*)d_in[0];      // [16,64,64,64]
    const float* e = (const float*)d_in[1];      // [64,1024]
    float* out = (float*)d_out;

    float* sum = (float*)d_ws;
    unsigned* tick = (unsigned*)d_ws + 2;
    float* enh = (float*)d_ws + WS_ENH_F;
    unsigned short* ehT = (unsigned short*)((char*)d_ws + WS_EHT_BYTE);
    unsigned short* elT = (unsigned short*)((char*)d_ws + WS_ELT_BYTE);

    prep_kernel<<<256, 256, 0, stream>>>(e, enh, ehT, elT, sum, tick);
    vq_gemm<<<NPTS / 64, 256, 0, stream>>>(x, e, enh, ehT, elT, out, sum, tick);
}

// Round 2
// 136.662 us; speedup vs baseline: 1.0287x; 1.0287x over previous
//
#include <hip/hip_runtime.h>

// VectorQuantizer: B=16, D=64, H=64, W=64, K=1024
#define DD 64
#define KK 1024
#define NPTS 65536
#define TOTAL 4194304

// Output layout (flat f32): quantized[4194304], L1, L2, idx[65536]
#define OFF_L1 4194304
#define OFF_L2 4194305
#define OFF_IDX 4194306

// ws layout (bytes): [0] f32 sum, [8] u32 ticket, enh @ float 64 (byte 256),
// ehT @ byte 65536 (128KB), elT @ byte 196608 (128KB). (<=328KB used)
#define WS_ENH_F 64
#define WS_EHT_BYTE 65536
#define WS_ELT_BYTE (65536 + 131072)

// score = dot(x,e) + 512 - ||e||^2/2  (argmax == argmin distance; +512 keeps
// all scores positive so float bits are monotone -> packed uint compare).
// Rescue margin: 32-ulp granule (<=2e-3) + bf16x3 err (~6e-4) + slack.
#define MARGIN_S 0.006f

typedef __attribute__((ext_vector_type(8))) short short8;
typedef __attribute__((ext_vector_type(4))) float f32x4;

__device__ __forceinline__ unsigned short bf16_rne(float f) {
    unsigned b = __float_as_uint(f);
    return (unsigned short)((b + 0x7FFFu + ((b >> 16) & 1u)) >> 16);
}
__device__ __forceinline__ float bf16_to_f(unsigned short h) {
    return __uint_as_float(((unsigned)h) << 16);
}
__device__ __forceinline__ unsigned umax(unsigned a, unsigned b) { return a > b ? a : b; }
__device__ __forceinline__ unsigned umin(unsigned a, unsigned b) { return a < b ? a : b; }
// async global->LDS DMA, 16B per lane; LDS dest = wave-uniform base + lane*16
__device__ __forceinline__ void gld_lds16(const void* g, void* l) {
    __builtin_amdgcn_global_load_lds(
        (const __attribute__((address_space(1))) void*)g,
        (__attribute__((address_space(3))) void*)l, 16, 0, 0);
}
// swizzled position of element d within a 64-elem row r (16B-granule XOR key)
__device__ __forceinline__ int swz(int r, int d) {
    return ((d & ~7) ^ ((r & 7) << 3)) | (d & 7);
}

// ---------- kernel 1: enh + swizzled bf16 hi/lo codebook [k][64] ----------
__global__ __launch_bounds__(256) void prep_kernel(const float* __restrict__ e,
                                                   float* __restrict__ enh,
                                                   unsigned short* __restrict__ ehT,
                                                   unsigned short* __restrict__ elT,
                                                   float* __restrict__ sum,
                                                   unsigned* __restrict__ tick) {
    const int tid = threadIdx.x;
    if (blockIdx.x == 0 && tid == 0) { *sum = 0.f; *tick = 0u; }
    const int wave = tid >> 6, lane = tid & 63;
    const int k = blockIdx.x * 4 + wave;      // this wave's code
    const float v = e[lane * KK + k];         // lane = d
    const unsigned short h = bf16_rne(v);
    const unsigned short l = bf16_rne(v - bf16_to_f(h));
    const int pos = k * 64 + swz(k, lane);
    ehT[pos] = h;
    elT[pos] = l;
    float s2 = v * v;
#pragma unroll
    for (int m = 32; m > 0; m >>= 1) s2 += __shfl_down(s2, m, 64);
    if (lane == 0) enh[k] = 512.0f - 0.5f * s2;
}

// ---------- kernel 2: MFMA bf16x3 + packed-key argmax + in-block exact rescue
//            + quantize (bf16 hi+lo reconstruct) + loss via score identity ----------
// 256 thr = 4 waves; block = 64 pts x 1024 codes (16 tiles of 64 codes).
// LDS = exactly 32KB (ebuf double buffer); x-prep and merge scratch alias into
// ebuf. __launch_bounds__(256,4): 4 blocks/CU co-resident (grid = 4/CU exactly)
// with VGPR cap 128 -- NOT 5: the (256,5) variant forced VGPR=48 and spilled
// the persistent A-frags/accumulators (dur 58->89us, WRITE +4MB scratch).
__global__ __launch_bounds__(256, 4) void vq_gemm(const float* __restrict__ x,
                                                  const float* __restrict__ e,
                                                  const float* __restrict__ enh,
                                                  const unsigned short* __restrict__ ehT,
                                                  const unsigned short* __restrict__ elT,
                                                  float* __restrict__ out,
                                                  float* __restrict__ sum,
                                                  unsigned* __restrict__ tick) {
    __shared__ __align__(16) char ebuf[2 * 16384];   // the ONLY LDS (32KB)

    // post-loop aliases into ebuf[0] (holds tile 14; dead once every wave has
    // passed kt=15's top barrier -- kt=15 reads only ebuf[1])
    float* mv1 = (float*)ebuf;          // [128]
    float* mv2 = mv1 + 128;             // [128]
    int*   mi1 = (int*)(mv2 + 128);     // [128]
    int*   ks  = mi1 + 128;             // [64]
    float* xnp = (float*)(ks + 64);     // [64]  ||x_p||^2
    float* lv  = xnp + 64;              // [64]  per-point loss term
    float* xp  = lv + 64;               // [64]  rescue point
    int*   rl  = (int*)(xp + 64);       // [64]  ambiguous-point list
    int*   rn  = rl + 64;               // [1]
    float* rv  = (float*)(rn + 1);      // [4]
    int*   ri  = (int*)(rv + 4);        // [4]

    const int tid = threadIdx.x;
    const int wave = tid >> 6, lane = tid & 63;
    const int n0 = blockIdx.x * 64;
    const int b = n0 >> 12;
    const int hw0 = n0 & 4095;

    const char* ehTb = (const char*)ehT;
    const char* elTb = (const char*)elT;
    const int lofs = wave * 1024 + lane * 16;   // per-lane byte offset in a pass

    // issue tile-0 DMA immediately (lands during x-prep)
    {
        char* db = ebuf;
        gld_lds16(ehTb + lofs,        db + wave * 1024);
        gld_lds16(ehTb + 4096 + lofs, db + 4096 + wave * 1024);
        gld_lds16(elTb + lofs,        db + 8192 + wave * 1024);
        gld_lds16(elTb + 4096 + lofs, db + 12288 + wave * 1024);
    }

    // ---- x prep, entirely inside ebuf[1]: fp32 stage -> regs -> bf16 hi/lo ----
    float* xsc = (float*)(ebuf + 16384);        // 16KB fp32 scratch (= buf1)
    {
        const int d = tid >> 2, ph = tid & 3;
        const float* src = x + ((b * DD + d) << 12) + hw0 + ph * 16;
        float* dst = xsc + d * 64 + ph * 16;
#pragma unroll
        for (int j = 0; j < 4; ++j)
            *(float4*)(dst + j * 4) = *(const float4*)(src + j * 4);
    }
    __syncthreads();
    const int p = tid >> 2, dq = tid & 3;
    float xv[16];
    float xn = 0.f;
#pragma unroll
    for (int s = 0; s < 16; ++s) {
        xv[s] = xsc[(dq * 16 + s) * 64 + p];
        xn = fmaf(xv[s], xv[s], xn);
    }
    xn += __shfl_down(xn, 1, 64);
    xn += __shfl_down(xn, 2, 64);   // dq==0 lane now holds ||x_p||^2
    __syncthreads();                // all xsc reads done; safe to overwrite
    unsigned short* xbh = (unsigned short*)(ebuf + 16384);
    unsigned short* xbl = (unsigned short*)(ebuf + 16384 + 8192);
    {
#pragma unroll
        for (int g = 0; g < 2; ++g) {
            short8 hh, ll;
#pragma unroll
            for (int j = 0; j < 8; ++j) {
                const float f = xv[g * 8 + j];
                const unsigned short h = bf16_rne(f);
                hh[j] = (short)h;
                ll[j] = (short)bf16_rne(f - bf16_to_f(h));
            }
            const int pos = p * 64 + ((dq * 16 + g * 8) ^ ((p & 7) << 3));
            *(short8*)(xbh + pos) = hh;
            *(short8*)(xbl + pos) = ll;
        }
    }
    __syncthreads();

    const int ln15 = lane & 15, q8 = (lane >> 4) * 8;
    const int wp = (wave >> 1) * 32;   // point base of this wave
    const int wc = (wave & 1) * 32;    // code base within tile

    short8 ah[2][2], al[2][2];         // persistent A frags [rf][kc]
#pragma unroll
    for (int rf = 0; rf < 2; ++rf)
#pragma unroll
        for (int kc = 0; kc < 2; ++kc) {
            const int pp = wp + rf * 16 + ln15;
            const int pos = pp * 64 + ((kc * 32 + q8) ^ ((pp & 7) << 3));
            ah[rf][kc] = *(const short8*)(xbh + pos);
            al[rf][kc] = *(const short8*)(xbl + pos);
        }

    unsigned v1u[8], v2u[8];
#pragma unroll
    for (int r = 0; r < 8; ++r) { v1u[r] = 0u; v2u[r] = 0u; }

    for (int kt = 0; kt < 16; ++kt) {
        __syncthreads();   // drains tile-kt DMA + all waves done with kt-1
        if (kt < 15) {     // stream tile kt+1 into the other buffer
            const int nkt = kt + 1;
            char* db = ebuf + (nkt & 1) * 16384;
            const char* sH = ehTb + nkt * 8192 + lofs;
            const char* sL = elTb + nkt * 8192 + lofs;
            gld_lds16(sH,        db + wave * 1024);
            gld_lds16(sH + 4096, db + 4096 + wave * 1024);
            gld_lds16(sL,        db + 8192 + wave * 1024);
            gld_lds16(sL + 4096, db + 12288 + wave * 1024);
        }
        const unsigned short* ebH = (const unsigned short*)(ebuf + (kt & 1) * 16384);
        const unsigned short* ebL = ebH + 4096;

        // acc init = 512 - ||e||^2/2 (biased argmax score)
        f32x4 acc[2][2];
#pragma unroll
        for (int cf = 0; cf < 2; ++cf) {
            const float ec = enh[kt * 64 + wc + cf * 16 + ln15];
#pragma unroll
            for (int rf = 0; rf < 2; ++rf)
                acc[rf][cf] = (f32x4){ec, ec, ec, ec};
        }

#pragma unroll
        for (int kc = 0; kc < 2; ++kc) {
            short8 bh[2], bl[2];
#pragma unroll
            for (int cf = 0; cf < 2; ++cf) {
                const int c = wc + cf * 16 + ln15;
                const int pos = c * 64 + ((kc * 32 + q8) ^ ((c & 7) << 3));
                bh[cf] = *(const short8*)(ebH + pos);
                bl[cf] = *(const short8*)(ebL + pos);
            }
#pragma unroll
            for (int rf = 0; rf < 2; ++rf)
#pragma unroll
                for (int cf = 0; cf < 2; ++cf) {
                    acc[rf][cf] = __builtin_amdgcn_mfma_f32_16x16x32_bf16(al[rf][kc], bh[cf], acc[rf][cf], 0, 0, 0);
                    acc[rf][cf] = __builtin_amdgcn_mfma_f32_16x16x32_bf16(ah[rf][kc], bl[cf], acc[rf][cf], 0, 0, 0);
                    acc[rf][cf] = __builtin_amdgcn_mfma_f32_16x16x32_bf16(ah[rf][kc], bh[cf], acc[rf][cf], 0, 0, 0);
                }
        }

        // packed-key top-2 per (rf,reg) row: key = (bits|31) ^ col5
        // (low5 = 31^col5 -> umax tie-breaks toward SMALLER col5 = smaller k)
#pragma unroll
        for (int rf = 0; rf < 2; ++rf)
#pragma unroll
            for (int reg = 0; reg < 4; ++reg) {
                const int r = rf * 4 + reg;
                const unsigned k0 = (__float_as_uint(acc[rf][0][reg]) | 31u) ^ (unsigned)(kt * 2 + 0);
                const unsigned k1 = (__float_as_uint(acc[rf][1][reg]) | 31u) ^ (unsigned)(kt * 2 + 1);
                const unsigned a = umax(k0, k1), bb = umin(k0, k1);
                v2u[r] = umax(umax(v2u[r], umin(v1u[r], a)), bb);
                v1u[r] = umax(v1u[r], a);
            }
    }

    // ebuf[0] is now dead (kt=15 read ebuf[1]); publish prologue-held state
    if ((tid & 3) == 0) xnp[p] = xn;
    if (tid == 0) *rn = 0;

    // decode + cross-lane merge within the 16 lanes sharing each row-set
#pragma unroll
    for (int r = 0; r < 8; ++r) {
        const unsigned c5 = 31u - (v1u[r] & 31u);
        int col = (int)(c5 >> 1) * 64 + wc + (int)(c5 & 1) * 16 + ln15;
        float val = __uint_as_float(v1u[r] & ~31u);
        float sec = __uint_as_float(v2u[r] & ~31u);
#pragma unroll
        for (int msk = 1; msk < 16; msk <<= 1) {
            const float ov = __shfl_xor(val, msk);
            const int oc = __shfl_xor(col, msk);
            const float os = __shfl_xor(sec, msk);
            sec = fmaxf(fmaxf(sec, os), fminf(val, ov));
            const bool t = (ov > val) || (ov == val && oc < col);
            val = t ? ov : val;
            col = t ? oc : col;
        }
        if (ln15 == 0) {
            const int q = lane >> 4;
            const int h = wave & 1;
            const int pt = wp + (r >> 2) * 16 + q * 4 + (r & 3);
            mv1[pt * 2 + h] = val;
            mi1[pt * 2 + h] = col;
            mv2[pt * 2 + h] = sec;
        }
    }
    __syncthreads();
    if (tid < 64) {   // merge the two code-half waves (argmax, tie -> smaller idx)
        const float va = mv1[tid * 2], vb = mv1[tid * 2 + 1];
        const int ia = mi1[tid * 2], ib = mi1[tid * 2 + 1];
        const bool t = (vb > va) || (vb == va && ib < ia);
        const float bv = t ? vb : va;
        const int bi = t ? ib : ia;
        const float sec = fmaxf(fmaxf(mv2[tid * 2], mv2[tid * 2 + 1]), fminf(va, vb));
        ks[tid] = bi;
        // loss via identity: ||x-e||^2 = ||x||^2 + 1024 - 2*score
        // midpoint decode (|16 = half the 32-ulp truncation granule) -> unbiased
        const float bmid = __uint_as_float(__float_as_uint(bv) | 16u);
        lv[tid] = xnp[tid] + 1024.0f - 2.0f * bmid;
        if (bv - sec < MARGIN_S) {    // ambiguous under granule+bf16x3 bound
            const int w = atomicAdd(rn, 1);
            rl[w] = tid;              // <=64 entries possible
        }
    }
    __syncthreads();

    // ---- in-block exact fp32 rescue (expected ~0.16 items/block) ----
    const int lcnt = *rn;
    for (int it = 0; it < lcnt; ++it) {
        const int pr = rl[it];
        if (tid < 64) xp[tid] = x[((b * DD + tid) << 12) + hw0 + pr];
        __syncthreads();
        float d0 = 0.f, d1 = 0.f, d2 = 0.f, d3 = 0.f;
#pragma unroll 8
        for (int dd = 0; dd < DD; ++dd) {
            const float xd = xp[dd];
            const float4 ev = *(const float4*)(e + dd * KK + tid * 4);
            d0 = fmaf(xd, ev.x, d0);
            d1 = fmaf(xd, ev.y, d1);
            d2 = fmaf(xd, ev.z, d2);
            d3 = fmaf(xd, ev.w, d3);
        }
        const float4 ea = *(const float4*)(enh + tid * 4);
        float bs = d0 + ea.x;
        int bi2 = tid * 4;
        if (d1 + ea.y > bs) { bs = d1 + ea.y; bi2 = tid * 4 + 1; }
        if (d2 + ea.z > bs) { bs = d2 + ea.z; bi2 = tid * 4 + 2; }
        if (d3 + ea.w > bs) { bs = d3 + ea.w; bi2 = tid * 4 + 3; }
#pragma unroll
        for (int m = 1; m < 64; m <<= 1) {
            const float ov = __shfl_xor(bs, m, 64);
            const int oi = __shfl_xor(bi2, m, 64);
            if (ov > bs || (ov == bs && oi < bi2)) { bs = ov; bi2 = oi; }
        }
        if (lane == 0) { rv[wave] = bs; ri[wave] = bi2; }
        __syncthreads();
        if (tid == 0) {
            float gs = rv[0];
            int gi = ri[0];
#pragma unroll
            for (int t2 = 1; t2 < 4; ++t2)
                if (rv[t2] > gs || (rv[t2] == gs && ri[t2] < gi)) { gs = rv[t2]; gi = ri[t2]; }
            ks[pr] = gi;
            lv[pr] = xnp[pr] + 1024.0f - 2.0f * gs;   // exact score
        }
        __syncthreads();
    }

    // ---- idx out + block loss add + ticketed grid finalize ----
    if (tid < 64) {
        out[OFF_IDX + n0 + tid] = (float)ks[tid];
        float lc = lv[tid];
#pragma unroll
        for (int off = 32; off > 0; off >>= 1) lc += __shfl_down(lc, off, 64);
        if (tid == 0) {
            atomicAdd(sum, lc);
            __threadfence();
            const unsigned old = atomicAdd(tick, 1u);
            if (old == (unsigned)(gridDim.x - 1)) {
                const float s = atomicAdd(sum, 0.0f);
                const float m = s * (1.0f / (float)TOTAL);
                out[OFF_L1] = m;   // dictionary_loss
                out[OFF_L2] = m;   // commitment_loss (numerically identical)
            }
        }
    }

    // ---- quantize epilogue: reconstruct e from bf16 hi+lo (err <= ~3e-5) ----
    {
        const int pe = tid & 63, dqr = tid >> 6;
        const int kp = ks[pe];
        const int kx = (kp & 7) << 3;
        float qa[16];
#pragma unroll
        for (int g = 0; g < 2; ++g) {
            const int pos = kp * 64 + ((dqr * 16 + g * 8) ^ kx);
            const short8 h8 = *(const short8*)(ehT + pos);
            const short8 l8 = *(const short8*)(elT + pos);
#pragma unroll
            for (int j = 0; j < 8; ++j)
                qa[g * 8 + j] = bf16_to_f((unsigned short)h8[j]) + bf16_to_f((unsigned short)l8[j]);
        }
        float* ob = out + ((b * DD + dqr * 16) << 12) + hw0 + pe;
#pragma unroll
        for (int s = 0; s < 16; ++s) ob[s << 12] = qa[s];
    }
}

extern "C" void kernel_launch(void* const* d_in, const int* in_sizes, int n_in,
                              void* d_out, int out_size, void* d_ws, size_t ws_size,
                              hipStream_t stream) {
    const float* x = (const float*)d_in[0];      // [16,64,64,64]
    const float* e = (const float*)d_in[1];      // [64,1024]
    float* out = (float*)d_out;

    float* sum = (float*)d_ws;
    unsigned* tick = (unsigned*)d_ws + 2;
    float* enh = (float*)d_ws + WS_ENH_F;
    unsigned short* ehT = (unsigned short*)((char*)d_ws + WS_EHT_BYTE);
    unsigned short* elT = (unsigned short*)((char*)d_ws + WS_ELT_BYTE);

    prep_kernel<<<256, 256, 0, stream>>>(e, enh, ehT, elT, sum, tick);
    vq_gemm<<<NPTS / 64, 256, 0, stream>>>(x, e, enh, ehT, elT, out, sum, tick);
}